// Round 15
// baseline (104.811 us; speedup 1.0000x reference)
//
#include <hip/hip_runtime.h>
#include <math.h>

#define D_    256
#define NE    512
#define NNODE 64
#define NHEAD 4
#define SLOPE 0.2f
#define BTN   65536

typedef __attribute__((ext_vector_type(4))) float f32x4;
typedef __attribute__((ext_vector_type(8))) _Float16 f16x8;
typedef __attribute__((ext_vector_type(2))) _Float16 f16x2;
typedef __attribute__((ext_vector_type(2))) __fp16   h16x2;   // builtin interop
typedef unsigned short u16;

__device__ inline u16 f2h(float x) {
    union { _Float16 h; u16 u; } v; v.h = (_Float16)x; return v.u;
}
__device__ inline f16x2 pkrtz(float lo, float hi) {
    h16x2 r = __builtin_amdgcn_cvt_pkrtz(lo, hi);
    f16x2 o; __builtin_memcpy(&o, &r, 4); return o;
}

#define GLD16(g, l) __builtin_amdgcn_global_load_lds( \
    (const __attribute__((address_space(1))) void*)(g), \
    (__attribute__((address_space(3))) void*)(l), 16, 0, 0)

// ---------------------------------------------------------------------------
// Edge table: pack (src<<8)|dst and log(A0+eps) into one int2. One block.
// ---------------------------------------------------------------------------
__global__ __launch_bounds__(512) void build_edge(const int* __restrict__ src,
    const int* __restrict__ dst, const float* __restrict__ A0,
    int2* __restrict__ gedge)
{
    const int t = threadIdx.x;
    int s = src[t], d = dst[t];
    float lg = logf(A0[s * NNODE + d] + 1e-8f);
    gedge[t] = make_int2((s << 8) | d, __float_as_int(lg));
}

// Three 256x256 weights -> fp16 in one launch (192 blocks).
__global__ __launch_bounds__(256) void prep_w3(const float* __restrict__ w0,
    const float* __restrict__ w1, const float* __restrict__ w2,
    u16* __restrict__ h0, u16* __restrict__ h1, u16* __restrict__ h2)
{
    int sel = blockIdx.x >> 6, b = blockIdx.x & 63;
    const float* s = sel == 0 ? w0 : sel == 1 ? w1 : w2;
    u16* h = sel == 0 ? h0 : sel == 1 ? h1 : h2;
    int i = b * 256 + threadIdx.x;
    float4 v = ((const float4*)s)[i];
    ((ushort4*)h)[i] = make_ushort4(f2h(v.x), f2h(v.y), f2h(v.z), f2h(v.w));
}

// ---------------------------------------------------------------------------
// Fused GEMM1+2: [Xq|Xv] = H(fp32) x [W_lin|W_val]^T(fp16, 512 rows).
// LDS 32KB total: sA(10K)+sB(8K) during loop; epilogue bounce sT aliases the
// full 32KB after the loop's final barrier (sA/sB dead). 4 blocks/CU.
// A: reg-staged fp32->fp16, next-step loads issued early (T14 split).
// Epilogue: n-quadrant 0,1 -> Q slices [node][dim] chunk^=(node&7);
//           n-quadrant 2,3 -> V^T slices [dim][node] chunk^=(dim&7).
// ---------------------------------------------------------------------------
__global__ __launch_bounds__(256) void gemm12(const float* __restrict__ A32,
    const u16* __restrict__ B, u16* __restrict__ Xqh, u16* __restrict__ Xvt)
{
    __shared__ u16 smem[16384];                      // 32 KB
    u16* sA = smem;                                  // [128][40] padded, 10 KB
    u16* sB = smem + 5120;                           // [128][32] linear, 8 KB
    const int t = threadIdx.x, lane = t & 63, wave = t >> 6;
    const int wm = wave >> 1, wn = wave & 1;
    const int bid = blockIdx.x;
    const int swz = (bid & 7) * 256 + (bid >> 3);    // XCD-contiguous, bijective
    const int m0 = (swz >> 2) * 128, nq = swz & 3, n0 = nq * 128;
    const int fr = lane & 15, kq = (lane >> 4) * 8;
    const int arow_ = t >> 2, ac8 = (t & 3) * 8;     // A-staging coords

    f32x4 acc[4][4];
    #pragma unroll
    for (int i = 0; i < 4; ++i)
        #pragma unroll
        for (int j = 0; j < 4; ++j) acc[i][j] = 0.f;

    // prologue: A loads for k0 = 0
    float4 pv0[2], pv1[2];
    #pragma unroll
    for (int rr = 0; rr < 2; ++rr) {
        const float* ap = A32 + (size_t)(m0 + rr * 64 + arow_) * D_ + ac8;
        pv0[rr] = *(const float4*)ap;
        pv1[rr] = *(const float4*)(ap + 4);
    }

    for (int k0 = 0; k0 < D_; k0 += 32) {
        // ---- convert + ds_write current A regs ----
        #pragma unroll
        for (int rr = 0; rr < 2; ++rr) {
            f16x8 hv;
            hv[0] = (_Float16)pv0[rr].x; hv[1] = (_Float16)pv0[rr].y;
            hv[2] = (_Float16)pv0[rr].z; hv[3] = (_Float16)pv0[rr].w;
            hv[4] = (_Float16)pv1[rr].x; hv[5] = (_Float16)pv1[rr].y;
            hv[6] = (_Float16)pv1[rr].z; hv[7] = (_Float16)pv1[rr].w;
            *(f16x8*)&sA[(rr * 64 + arow_) * 40 + ac8] = hv;
        }
        // ---- B: GLD16, 512 chunks over 2 rounds ----
        #pragma unroll
        for (int s = 0; s < 2; ++s) {
            const int cb = (s * 4 + wave) * 64;
            const int c  = cb + lane;
            const int row = c >> 2, ks = (c & 3) * 8;
            GLD16(B + (size_t)(n0 + row) * D_ + k0 + ks, sB + cb * 8);
        }
        // ---- issue next-step A loads early (drain overlaps B's GLD16) ----
        if (k0 + 32 < D_) {
            #pragma unroll
            for (int rr = 0; rr < 2; ++rr) {
                const float* ap = A32 + (size_t)(m0 + rr * 64 + arow_) * D_
                                + k0 + 32 + ac8;
                pv0[rr] = *(const float4*)ap;
                pv1[rr] = *(const float4*)(ap + 4);
            }
        }
        __syncthreads();

        f16x8 fa[4];
        #pragma unroll
        for (int mi = 0; mi < 4; ++mi)
            fa[mi] = *(const f16x8*)(sA + (wm * 64 + mi * 16 + fr) * 40 + kq);
        #pragma unroll
        for (int ni = 0; ni < 4; ++ni) {
            f16x8 fb = *(const f16x8*)(sB + (wn * 64 + ni * 16 + fr) * 32 + kq);
            #pragma unroll
            for (int mi = 0; mi < 4; ++mi)
                acc[mi][ni] = __builtin_amdgcn_mfma_f32_16x16x32_f16(fa[mi], fb, acc[mi][ni], 0, 0, 0);
        }
        __syncthreads();   // after last iter: sA/sB dead -> sT may alias below
    }

    // ---- epilogue: wave quadrant = one (bt,h) 64x64 slice; sT = full smem ----
    const int fq = (lane >> 4) * 4;   // C/D: col = lane&15, row = (lane>>4)*4 + reg
    u16* wT = smem + wave * 4096;
    const bool isQ = nq < 2;
    #pragma unroll
    for (int mi = 0; mi < 4; ++mi)
        #pragma unroll
        for (int ni = 0; ni < 4; ++ni) {
            int node0 = mi * 16 + fq;              // r = 0..3 consecutive nodes
            int dim   = ni * 16 + fr;
            if (!isQ) {                            // V^T: [dim][node], chunk^=dim&7
                ushort4 v = make_ushort4(f2h(acc[mi][ni][0]), f2h(acc[mi][ni][1]),
                                         f2h(acc[mi][ni][2]), f2h(acc[mi][ni][3]));
                *(ushort4*)&wT[dim * 64 + (((node0 >> 3) ^ (dim & 7)) << 3) + (node0 & 7)] = v;
            } else {                               // Q: [node][dim], chunk^=node&7
                #pragma unroll
                for (int r = 0; r < 4; ++r) {
                    int node = node0 + r;
                    wT[node * 64 + ((((dim >> 3) ^ (node & 7))) << 3) + (dim & 7)]
                        = f2h(acc[mi][ni][r]);
                }
            }
        }
    __syncthreads();
    const int btq = (m0 >> 6) + wm;
    const int hq  = isQ ? (n0 >> 6) + wn : ((n0 - 256) >> 6) + wn;
    u16* gx = (isQ ? Xqh : Xvt) + ((size_t)btq * NHEAD + hq) * 4096;
    #pragma unroll
    for (int r = 0; r < 8; ++r)
        *(f16x8*)&gx[r * 512 + lane * 8] = *(const f16x8*)&wT[r * 512 + lane * 8];
}

// ---------------------------------------------------------------------------
// GEMM3: out = Yh(fp16) x W_out^T(fp16), fp32 row-major out. GLD16 staging.
// ---------------------------------------------------------------------------
__global__ __launch_bounds__(256) void gemm3(const u16* __restrict__ A,
    const u16* __restrict__ B, float* __restrict__ Cout)
{
    __shared__ u16 sA[4096], sB[4096];
    const int t = threadIdx.x, lane = t & 63, wave = t >> 6;
    const int wm = wave >> 1, wn = wave & 1;
    const int bid = blockIdx.x;
    const int swz = (bid & 7) * 128 + (bid >> 3);
    const int m0 = (swz >> 1) * 128, n0 = (swz & 1) * 128;
    const int fr = lane & 15, kq = (lane >> 4) * 8;

    f32x4 acc[4][4];
    #pragma unroll
    for (int i = 0; i < 4; ++i)
        #pragma unroll
        for (int j = 0; j < 4; ++j) acc[i][j] = 0.f;

    for (int k0 = 0; k0 < D_; k0 += 32) {
        #pragma unroll
        for (int s = 0; s < 2; ++s) {
            const int cb = (s * 4 + wave) * 64;
            const int c  = cb + lane;
            const int row = c >> 2, ks = (c & 3) * 8;
            GLD16(A + (size_t)(m0 + row) * D_ + k0 + ks, sA + cb * 8);
            GLD16(B + (size_t)(n0 + row) * D_ + k0 + ks, sB + cb * 8);
        }
        __syncthreads();

        f16x8 fa[4];
        #pragma unroll
        for (int mi = 0; mi < 4; ++mi)
            fa[mi] = *(const f16x8*)(sA + (wm * 64 + mi * 16 + fr) * 32 + kq);
        #pragma unroll
        for (int ni = 0; ni < 4; ++ni) {
            f16x8 fb = *(const f16x8*)(sB + (wn * 64 + ni * 16 + fr) * 32 + kq);
            #pragma unroll
            for (int mi = 0; mi < 4; ++mi)
                acc[mi][ni] = __builtin_amdgcn_mfma_f32_16x16x32_f16(fa[mi], fb, acc[mi][ni], 0, 0, 0);
        }
        __syncthreads();
    }

    const int fq = (lane >> 4) * 4;
    #pragma unroll
    for (int mi = 0; mi < 4; ++mi)
        #pragma unroll
        for (int ni = 0; ni < 4; ++ni)
            #pragma unroll
            for (int r = 0; r < 4; ++r) {
                int m = m0 + wm * 64 + mi * 16 + fq + r;
                int n = n0 + wn * 64 + ni * 16 + fr;
                Cout[(size_t)m * D_ + n] = acc[mi][ni][r];
            }
}

// ---------------------------------------------------------------------------
// Fused edge scores + softmax + aggregation, one block per (bt, head).
// (unchanged: MFMA edge scores, hoisted linear term, edge-parallel atomics,
//  MFMA aggregation; LDS ~28.9KB)
// ---------------------------------------------------------------------------
__global__ __launch_bounds__(256, 5) void fused_edge_agg(
    const u16* __restrict__ Xqh, const u16* __restrict__ Xvt,
    const int2* __restrict__ gedge, const float* __restrict__ a,
    u16* __restrict__ Yh)
{
    __shared__ u16   sQ[4096];    // 8 KB  Q fp16 swizzled; later P fp16 (swz)
    __shared__ float sP[4096];    // 16 KB P f32 [src][dst]
    __shared__ float sBn[NNODE];  // b[n] = <q_n, a>
    __shared__ float sLin[NE];    // 0.6*(b_s+b_d) + logA0
    __shared__ int   sPack[NE];   // (src<<8)|dst

    const int t = threadIdx.x, lane = t & 63, wave = t >> 6;
    const int fr = lane & 15, qtr = lane >> 4;
    const int bt = blockIdx.x >> 2, h = blockIdx.x & 3;

    // ---- V^T fragments: direct global -> register (chunk ^= dim&7 baked) ----
    const u16* gv = Xvt + ((size_t)bt * NHEAD + h) * 4096;
    f16x8 vf[2][4];
    #pragma unroll
    for (int kk = 0; kk < 2; ++kk) {
        int g = kk * 4 + qtr;
        #pragma unroll
        for (int mi = 0; mi < 4; ++mi) {
            int arow = mi * 16 + fr;
            vf[kk][mi] = *(const f16x8*)&gv[arow * 64 + ((g ^ (arow & 7)) << 3)];
        }
    }
    // ---- B-fragments for the score MFMA: 0.4*a, replicated rows ----
    f16x8 af[2];
    #pragma unroll
    for (int kk = 0; kk < 2; ++kk) {
        const float* ab = a + h * 64 + kk * 32 + qtr * 8;
        float4 a0 = *(const float4*)ab, a1 = *(const float4*)(ab + 4);
        af[kk][0] = (_Float16)(0.4f * a0.x); af[kk][1] = (_Float16)(0.4f * a0.y);
        af[kk][2] = (_Float16)(0.4f * a0.z); af[kk][3] = (_Float16)(0.4f * a0.w);
        af[kk][4] = (_Float16)(0.4f * a1.x); af[kk][5] = (_Float16)(0.4f * a1.y);
        af[kk][6] = (_Float16)(0.4f * a1.z); af[kk][7] = (_Float16)(0.4f * a1.w);
    }

    // ---- stage Q (already swizzled in global); zero P ----
    const u16* gq = Xqh + ((size_t)bt * NHEAD + h) * 4096;
    #pragma unroll
    for (int r = 0; r < 2; ++r) {
        int id = r * 256 + t;
        GLD16(gq + id * 8, (char*)sQ + id * 16);
    }
    #pragma unroll
    for (int i = 0; i < 4; ++i)
        ((float4*)sP)[t + i * 256] = make_float4(0.f, 0.f, 0.f, 0.f);
    __syncthreads();

    // ---- b[n] = <q_n, a>: 4 threads per node, 16 dims each (swizzled read) ----
    {
        int n = t >> 2, qq = t & 3;
        float b = 0.f;
        #pragma unroll
        for (int j = 0; j < 2; ++j) {
            int ck = qq * 2 + j;
            f16x8 qv = *(const f16x8*)&sQ[n * 64 + ((ck ^ (n & 7)) << 3)];
            const float* ab = a + h * 64 + ck * 8;
            float4 a0 = *(const float4*)ab, a1 = *(const float4*)(ab + 4);
            b = fmaf((float)qv[0], a0.x, b); b = fmaf((float)qv[1], a0.y, b);
            b = fmaf((float)qv[2], a0.z, b); b = fmaf((float)qv[3], a0.w, b);
            b = fmaf((float)qv[4], a1.x, b); b = fmaf((float)qv[5], a1.y, b);
            b = fmaf((float)qv[6], a1.z, b); b = fmaf((float)qv[7], a1.w, b);
        }
        b += __shfl_xor(b, 1);
        b += __shfl_xor(b, 2);
        if (qq == 0) sBn[n] = b;
    }
    __syncthreads();

    // ---- edge tables: sPack + hoisted linear term ----
    #pragma unroll
    for (int i = 0; i < 2; ++i) {
        int e = t + i * 256;
        int2 ge = gedge[e];
        int s_ = ge.x >> 8, d_ = ge.x & 255;
        sPack[e] = ge.x;
        sLin[e] = 0.6f * (sBn[s_] + sBn[d_]) + __int_as_float(ge.y);
    }
    __syncthreads();

    // ---- edge pass: 8 tiles/wave x 16 edges, scores via MFMA ----
    const int wbase = wave * 128;
    #pragma unroll
    for (int tt = 0; tt < 8; ++tt) {
        int e = wbase + tt * 16 + fr;
        int pk = sPack[e];
        int s_ = pk >> 8, d_ = pk & 255;
        f32x4 acc = 0.f;
        #pragma unroll
        for (int kk = 0; kk < 2; ++kk) {
            int ck = kk * 4 + qtr;
            f16x8 qs = *(const f16x8*)&sQ[s_ * 64 + ((ck ^ (s_ & 7)) << 3)];
            f16x8 qd = *(const f16x8*)&sQ[d_ * 64 + ((ck ^ (d_ & 7)) << 3)];
            f16x8 x = qs + qd;                       // 4x v_pk_add_f16
            unsigned xu[4];
            __builtin_memcpy(xu, &x, 16);
            xu[0] &= 0x7FFF7FFFu; xu[1] &= 0x7FFF7FFFu;
            xu[2] &= 0x7FFF7FFFu; xu[3] &= 0x7FFF7FFFu;
            f16x8 xa;
            __builtin_memcpy(&xa, xu, 16);
            acc = __builtin_amdgcn_mfma_f32_16x16x32_f16(xa, af[kk], acc, 0, 0, 0);
        }
        int c = lane & 15;
        if (c < 4) {
            float av = c == 0 ? acc[0] : c == 1 ? acc[1] : c == 2 ? acc[2] : acc[3];
            int eg = wbase + tt * 16 + qtr * 4 + c;
            int pk2 = sPack[eg];
            atomicAdd(&sP[(pk2 >> 8) * 64 + (pk2 & 255)], __expf(av + sLin[eg]));
        }
    }
    __syncthreads();

    // ---- convert: row-sum -> denom; normalize; fp16 into dead Q (swizzled) ----
    {
        int s_ = t >> 2, qq = t & 3;
        const float4* row = (const float4*)&sP[s_ * 64 + qq * 16];
        float4 v0 = row[0], v1 = row[1], v2 = row[2], v3 = row[3];
        float part = v0.x + v0.y + v0.z + v0.w + v1.x + v1.y + v1.z + v1.w
                   + v2.x + v2.y + v2.z + v2.w + v3.x + v3.y + v3.z + v3.w;
        part += __shfl_xor(part, 1);
        part += __shfl_xor(part, 2);
        float inv = part > 0.f ? 1.f / part : 0.f;
        f16x2 p0 = pkrtz(v0.x * inv, v0.y * inv), p1 = pkrtz(v0.z * inv, v0.w * inv);
        f16x2 p2 = pkrtz(v1.x * inv, v1.y * inv), p3 = pkrtz(v1.z * inv, v1.w * inv);
        f16x2 p4 = pkrtz(v2.x * inv, v2.y * inv), p5 = pkrtz(v2.z * inv, v2.w * inv);
        f16x2 p6 = pkrtz(v3.x * inv, v3.y * inv), p7 = pkrtz(v3.z * inv, v3.w * inv);
        int c0 = qq * 2, c1 = qq * 2 + 1;
        u16* d0 = &sQ[s_ * 64 + ((c0 ^ (s_ & 7)) << 3)];
        u16* d1 = &sQ[s_ * 64 + ((c1 ^ (s_ & 7)) << 3)];
        ((f16x2*)d0)[0] = p0; ((f16x2*)d0)[1] = p1;
        ((f16x2*)d0)[2] = p2; ((f16x2*)d0)[3] = p3;
        ((f16x2*)d1)[0] = p4; ((f16x2*)d1)[1] = p5;
        ((f16x2*)d1)[2] = p6; ((f16x2*)d1)[3] = p7;
    }
    __syncthreads();

    // ---- Y^T = V^T · P^T : wave owns 16 src nodes; 8 MFMAs (A from regs) ----
    f32x4 acc[4];
    #pragma unroll
    for (int i = 0; i < 4; ++i) acc[i] = 0.f;
    const int srow = wave * 16 + fr;
    #pragma unroll
    for (int kk = 0; kk < 2; ++kk) {
        int g = kk * 4 + qtr;
        f16x8 fb = *(const f16x8*)&sQ[srow * 64 + ((g ^ (srow & 7)) << 3)];
        #pragma unroll
        for (int mi = 0; mi < 4; ++mi)
            acc[mi] = __builtin_amdgcn_mfma_f32_16x16x32_f16(vf[kk][mi], fb, acc[mi], 0, 0, 0);
    }

    // ---- store: col = src node, row = dim ----
    const int node = wave * 16 + fr;
    const int fq = qtr * 4;
    u16* yh = Yh + ((size_t)bt * NNODE + node) * D_ + h * 64;
    #pragma unroll
    for (int mi = 0; mi < 4; ++mi) {
        ushort4 v = make_ushort4(f2h(acc[mi][0]), f2h(acc[mi][1]),
                                 f2h(acc[mi][2]), f2h(acc[mi][3]));
        *(ushort4*)&yh[mi * 16 + fq] = v;
    }
}

// ---------------------------------------------------------------------------
extern "C" void kernel_launch(void* const* d_in, const int* in_sizes, int n_in,
                              void* d_out, int out_size, void* d_ws, size_t ws_size,
                              hipStream_t stream)
{
    const float* H     = (const float*)d_in[0];
    const float* W_lin = (const float*)d_in[1];
    const float* W_val = (const float*)d_in[2];
    const float* a     = (const float*)d_in[3];
    const float* W_out = (const float*)d_in[4];
    const float* A0    = (const float*)d_in[5];
    const int*   src   = (const int*)d_in[6];
    const int*   dst   = (const int*)d_in[7];

    const size_t nX = (size_t)BTN * D_;              // 16777216 elems
    // ws layout: Xqh [0,32M) | Yh [32M,64M) | Wqv 256K | Wout 128K | gedge
    u16*  Xqh   = (u16*)d_ws;
    u16*  Yh    = Xqh + nX;
    u16*  Wqv   = Yh + nX;                           // 512 x 256 fp16
    u16*  Wouth = Wqv + 512 * D_;
    int2* gedge = (int2*)(Wouth + D_ * D_);
    if (ws_size < (size_t)134217728) return;

    u16* Xvt = (u16*)d_out;                          // d_out scratch until gemm3

    build_edge<<<1, 512, 0, stream>>>(src, dst, A0, gedge);
    prep_w3<<<192, 256, 0, stream>>>(W_lin, W_val, W_out,
                                     Wqv, Wqv + D_ * D_, Wouth);

    gemm12<<<2048, 256, 0, stream>>>(H, Wqv, Xqh, Xvt);

    fused_edge_agg<<<4096, 256, 0, stream>>>(Xqh, Xvt, gedge, a, Yh);

    gemm3<<<1024, 256, 0, stream>>>(Yh, Wouth, (float*)d_out);
}